// Round 1
// baseline (904.063 us; speedup 1.0000x reference)
//
#include <hip/hip_runtime.h>
#include <math.h>

namespace {

constexpr int kB  = 2;
constexpr int kS  = 2048;
constexpr int kD  = 512;
constexpr int kH  = 8;
constexpr int kDK = 64;
constexpr int kM  = kB * kS;   // 4096 rows
constexpr int kBH = kB * kH;   // 16

__device__ __forceinline__ float wave_sum64(float v) {
#pragma unroll
    for (int o = 32; o > 0; o >>= 1) v += __shfl_xor(v, o, 64);
    return v;
}
__device__ __forceinline__ float wave_max64(float v) {
#pragma unroll
    for (int o = 32; o > 0; o >>= 1) v = fmaxf(v, __shfl_xor(v, o, 64));
    return v;
}

#define MAXN_F  ((float)(1.0 - 1e-5))
#define ACLIP_F ((float)(1.0 - 1e-7))

// ------------------- GEMM: Y(M x 512) = X(M x 512) @ W(512 x 512)^T -------------------
__global__ __launch_bounds__(256) void gemm_xwt(const float* __restrict__ X,
                                                const float* __restrict__ W,
                                                float* __restrict__ Y) {
    __shared__ float As[16][68];
    __shared__ float Bs[16][68];
    const int bm = blockIdx.x * 64;
    const int bn = blockIdx.y * 64;
    const int tid = threadIdx.x;
    const int ty = tid >> 4, tx = tid & 15;
    const int lr = tid >> 2;
    const int lc = (tid & 3) * 4;
    float acc[4][4] = {};
    for (int k0 = 0; k0 < 512; k0 += 16) {
        float4 av = *(const float4*)(X + (size_t)(bm + lr) * 512 + k0 + lc);
        float4 bv = *(const float4*)(W + (size_t)(bn + lr) * 512 + k0 + lc);
        As[lc + 0][lr] = av.x; As[lc + 1][lr] = av.y; As[lc + 2][lr] = av.z; As[lc + 3][lr] = av.w;
        Bs[lc + 0][lr] = bv.x; Bs[lc + 1][lr] = bv.y; Bs[lc + 2][lr] = bv.z; Bs[lc + 3][lr] = bv.w;
        __syncthreads();
#pragma unroll
        for (int k = 0; k < 16; ++k) {
            float4 a = *(const float4*)&As[k][ty * 4];
            float4 b = *(const float4*)&Bs[k][tx * 4];
            float ar[4] = {a.x, a.y, a.z, a.w};
            float br[4] = {b.x, b.y, b.z, b.w};
#pragma unroll
            for (int i = 0; i < 4; ++i)
#pragma unroll
                for (int j = 0; j < 4; ++j) acc[i][j] = fmaf(ar[i], br[j], acc[i][j]);
        }
        __syncthreads();
    }
#pragma unroll
    for (int i = 0; i < 4; ++i) {
        *(float4*)(Y + (size_t)(bm + ty * 4 + i) * 512 + bn + tx * 4) =
            make_float4(acc[i][0], acc[i][1], acc[i][2], acc[i][3]);
    }
}

// --------- mobius_linear tail: res=matvec scale; mobius_add(res,b); project ---------
__global__ __launch_bounds__(256) void rowops(const float* __restrict__ X,
                                              const float* __restrict__ MX,
                                              const float* __restrict__ bvec,
                                              float* __restrict__ out) {
    __shared__ float4 red4[4];
    __shared__ float red1[4];
    const int row = blockIdx.x;
    const int tid = threadIdx.x;
    const float2 xv = ((const float2*)(X + (size_t)row * kD))[tid];
    const float2 mv = ((const float2*)(MX + (size_t)row * kD))[tid];
    const float2 bv = ((const float2*)bvec)[tid];
    float sx  = fmaf(xv.x, xv.x, xv.y * xv.y);
    float sm  = fmaf(mv.x, mv.x, mv.y * mv.y);
    float smb = fmaf(mv.x, bv.x, mv.y * bv.y);
    float sb  = fmaf(bv.x, bv.x, bv.y * bv.y);
#pragma unroll
    for (int o = 32; o > 0; o >>= 1) {
        sx  += __shfl_xor(sx, o, 64);
        sm  += __shfl_xor(sm, o, 64);
        smb += __shfl_xor(smb, o, 64);
        sb  += __shfl_xor(sb, o, 64);
    }
    if ((tid & 63) == 0) red4[tid >> 6] = make_float4(sx, sm, smb, sb);
    __syncthreads();
    {
        float4 r0 = red4[0], r1 = red4[1], r2 = red4[2], r3 = red4[3];
        sx  = r0.x + r1.x + r2.x + r3.x;
        sm  = r0.y + r1.y + r2.y + r3.y;
        smb = r0.z + r1.z + r2.z + r3.z;
        sb  = r0.w + r1.w + r2.w + r3.w;
    }
    float xn  = sqrtf(fmaxf(sx, 1e-15f));
    float mxn = sqrtf(fmaxf(sm, 1e-15f));
    float xc  = fminf(xn, ACLIP_F);
    float at  = 0.5f * logf((1.f + xc) / (1.f - xc));       // artanh(xn)
    float sc  = tanhf(mxn / xn * at) / mxn;                 // res = sc * mx
    if (sm == 0.f) sc = 0.f;                                // all(mx==0) branch
    float x2 = sc * sc * sm;
    float xy = sc * smb;
    float y2 = sb;
    float c1 = 1.f + 2.f * xy + y2;
    float c2 = 1.f - x2;
    float den = fmaxf(1.f + 2.f * xy + x2 * y2, 1e-15f);
    float idn = 1.f / den;
    float ux = (c1 * sc * mv.x + c2 * bv.x) * idn;
    float uy = (c1 * sc * mv.y + c2 * bv.y) * idn;
    float su = wave_sum64(fmaf(ux, ux, uy * uy));
    if ((tid & 63) == 0) red1[tid >> 6] = su;
    __syncthreads();
    su = (red1[0] + red1[1]) + (red1[2] + red1[3]);
    float n = sqrtf(fmaxf(su, 1e-15f));
    float f = (n > MAXN_F) ? (MAXN_F / n) : 1.f;
    ((float2*)(out + (size_t)row * kD))[tid] = make_float2(ux * f, uy * f);
}

// ---- prep: per-head-row |q|^2, |k|^2 and LV = logmap0(V_head), bh-major layout ----
__global__ __launch_bounds__(256) void prep(const float* __restrict__ Qp,
                                            const float* __restrict__ Kp,
                                            const float* __restrict__ Vp,
                                            float* __restrict__ qn2,
                                            float* __restrict__ kn2,
                                            float* __restrict__ LV) {
    const int gid  = blockIdx.x * 4 + (threadIdx.x >> 6); // 0..32767 = bh*2048+s
    const int lane = threadIdx.x & 63;
    const int bh = gid >> 11, s = gid & 2047;
    const int b = bh >> 3, h = bh & 7;
    const size_t src = (size_t)(b * kS + s) * kD + h * kDK + lane;
    float q = Qp[src], k = Kp[src], v = Vp[src];
    float sq = wave_sum64(q * q);
    float sk = wave_sum64(k * k);
    float sv = wave_sum64(v * v);
    if (lane == 0) { qn2[gid] = sq; kn2[gid] = sk; }
    float yn = sqrtf(fmaxf(sv, 1e-15f));
    float yc = fminf(yn, ACLIP_F);
    float coef = 0.5f * logf((1.f + yc) / (1.f - yc)) / yn;
    LV[(size_t)gid * kDK + lane] = v * coef;
}

// --------- scores: per (b,h) 128x128 tile of -dist/sqrt(dk), written raw ---------
__global__ __launch_bounds__(256) void scores_k(const float* __restrict__ Qp,
                                                const float* __restrict__ Kp,
                                                const float* __restrict__ qn2,
                                                const float* __restrict__ kn2,
                                                float* __restrict__ attn) {
    __shared__ float Qs[64][128];   // [d][m]
    __shared__ float Ks[64][128];   // [d][n]
    const int i0 = blockIdx.x * 128;
    const int j0 = blockIdx.y * 128;
    const int bh = blockIdx.z;
    const int b = bh >> 3, h = bh & 7;
    const int tid = threadIdx.x;
    for (int t = tid; t < 2048; t += 256) {
        const int r = t >> 4;
        const int c = (t & 15) * 4;
        float4 qv = *(const float4*)(Qp + (size_t)(b * kS + i0 + r) * kD + h * kDK + c);
        float4 kv = *(const float4*)(Kp + (size_t)(b * kS + j0 + r) * kD + h * kDK + c);
        Qs[c + 0][r] = qv.x; Qs[c + 1][r] = qv.y; Qs[c + 2][r] = qv.z; Qs[c + 3][r] = qv.w;
        Ks[c + 0][r] = kv.x; Ks[c + 1][r] = kv.y; Ks[c + 2][r] = kv.z; Ks[c + 3][r] = kv.w;
    }
    __syncthreads();
    const int ty = tid >> 4, tx = tid & 15;
    float acc[8][8] = {};
#pragma unroll 16
    for (int d = 0; d < 64; ++d) {
        float4 a0 = *(const float4*)&Qs[d][ty * 4];
        float4 a1 = *(const float4*)&Qs[d][64 + ty * 4];
        float4 b0 = *(const float4*)&Ks[d][tx * 4];
        float4 b1 = *(const float4*)&Ks[d][64 + tx * 4];
        float ar[8] = {a0.x, a0.y, a0.z, a0.w, a1.x, a1.y, a1.z, a1.w};
        float br[8] = {b0.x, b0.y, b0.z, b0.w, b1.x, b1.y, b1.z, b1.w};
#pragma unroll
        for (int i = 0; i < 8; ++i)
#pragma unroll
            for (int j = 0; j < 8; ++j) acc[i][j] = fmaf(ar[i], br[j], acc[i][j]);
    }
    float x2r[8], y2c[8];
#pragma unroll
    for (int i = 0; i < 8; ++i) {
        int ri = (i < 4) ? (ty * 4 + i) : (64 + ty * 4 + (i - 4));
        x2r[i] = qn2[(bh << 11) + i0 + ri];
    }
#pragma unroll
    for (int j = 0; j < 8; ++j) {
        int cj = (j < 4) ? (tx * 4 + j) : (64 + tx * 4 + (j - 4));
        y2c[j] = kn2[(bh << 11) + j0 + cj];
    }
#pragma unroll
    for (int i = 0; i < 8; ++i) {
        int ri = (i < 4) ? (ty * 4 + i) : (64 + ty * 4 + (i - 4));
        float* orow = attn + (size_t)((bh << 11) + i0 + ri) * kS + j0;
        float o[8];
#pragma unroll
        for (int j = 0; j < 8; ++j) {
            float xy = acc[i][j];
            float x2 = x2r[i], y2 = y2c[j];
            float A  = 1.f - 2.f * xy + y2;
            float Bc = 1.f - x2;
            float num2 = A * A * x2 + Bc * Bc * y2 - 2.f * A * Bc * xy;
            float den  = fmaxf(1.f - 2.f * xy + x2 * y2, 1e-15f);
            float t = sqrtf(fmaxf(num2, 0.f)) / den;
            t = fminf(t, ACLIP_F);
            float dist = __logf((1.f + t) / (1.f - t));  // = 2*artanh(t)
            o[j] = dist * -0.125f;                        // -dist/sqrt(64)
        }
        *(float4*)(orow + tx * 4)      = make_float4(o[0], o[1], o[2], o[3]);
        *(float4*)(orow + 64 + tx * 4) = make_float4(o[4], o[5], o[6], o[7]);
    }
}

// ------------------- softmax (in-place on attn rows) + w-normalizer -------------------
__global__ __launch_bounds__(256) void softmax_k(float* __restrict__ attn,
                                                 float* __restrict__ wsuminv) {
    __shared__ float red[4];
    const int row = blockIdx.x;
    float* p = attn + (size_t)row * kS;
    const int tid = threadIdx.x;
    float4 v0 = ((const float4*)p)[tid];
    float4 v1 = ((const float4*)p)[tid + 256];
    float m = fmaxf(fmaxf(fmaxf(v0.x, v0.y), fmaxf(v0.z, v0.w)),
                    fmaxf(fmaxf(v1.x, v1.y), fmaxf(v1.z, v1.w)));
    m = wave_max64(m);
    if ((tid & 63) == 0) red[tid >> 6] = m;
    __syncthreads();
    m = fmaxf(fmaxf(red[0], red[1]), fmaxf(red[2], red[3]));
    __syncthreads();
    float e[8] = {__expf(v0.x - m), __expf(v0.y - m), __expf(v0.z - m), __expf(v0.w - m),
                  __expf(v1.x - m), __expf(v1.y - m), __expf(v1.z - m), __expf(v1.w - m)};
    float s = ((e[0] + e[1]) + (e[2] + e[3])) + ((e[4] + e[5]) + (e[6] + e[7]));
    s = wave_sum64(s);
    if ((tid & 63) == 0) red[tid >> 6] = s;
    __syncthreads();
    s = (red[0] + red[1]) + (red[2] + red[3]);
    __syncthreads();
    float inv = 1.f / s;
    float pv[8];
#pragma unroll
    for (int i = 0; i < 8; ++i) pv[i] = e[i] * inv;
    float sp = ((pv[0] + pv[1]) + (pv[2] + pv[3])) + ((pv[4] + pv[5]) + (pv[6] + pv[7]));
    sp = wave_sum64(sp);
    if ((tid & 63) == 0) red[tid >> 6] = sp;
    __syncthreads();
    sp = (red[0] + red[1]) + (red[2] + red[3]);
    ((float4*)p)[tid]       = make_float4(pv[0], pv[1], pv[2], pv[3]);
    ((float4*)p)[tid + 256] = make_float4(pv[4], pv[5], pv[6], pv[7]);
    if (tid == 0) wsuminv[row] = 1.f / (sp + 1e-10f);
}

// ------------------- mid = (attn/(rowsum+1e-10)) @ LV, per (b,h) -------------------
__global__ __launch_bounds__(256) void pv_k(const float* __restrict__ attn,
                                            const float* __restrict__ LV,
                                            const float* __restrict__ wsuminv,
                                            float* __restrict__ mid) {
    __shared__ float As[64][128];  // [k][m]
    __shared__ float Ls[64][68];   // [k][n]
    const int i0 = blockIdx.x * 128;
    const int bh = blockIdx.y;
    const int tid = threadIdx.x;
    const int ty = tid >> 4, tx = tid & 15;
    float acc[8][4] = {};
    for (int k0 = 0; k0 < kS; k0 += 64) {
        for (int t = tid; t < 2048; t += 256) {
            const int r = t >> 4;
            const int c = (t & 15) * 4;
            float4 av = *(const float4*)(attn + (size_t)((bh << 11) + i0 + r) * kS + k0 + c);
            As[c + 0][r] = av.x; As[c + 1][r] = av.y; As[c + 2][r] = av.z; As[c + 3][r] = av.w;
        }
        for (int t = tid; t < 1024; t += 256) {
            const int r = t >> 4;
            const int c = (t & 15) * 4;
            *(float4*)&Ls[r][c] = *(const float4*)(LV + (size_t)((bh << 11) + k0 + r) * kDK + c);
        }
        __syncthreads();
#pragma unroll 16
        for (int k = 0; k < 64; ++k) {
            float4 a0 = *(const float4*)&As[k][ty * 4];
            float4 a1 = *(const float4*)&As[k][64 + ty * 4];
            float4 bb = *(const float4*)&Ls[k][tx * 4];
            float ar[8] = {a0.x, a0.y, a0.z, a0.w, a1.x, a1.y, a1.z, a1.w};
            float br[4] = {bb.x, bb.y, bb.z, bb.w};
#pragma unroll
            for (int i = 0; i < 8; ++i)
#pragma unroll
                for (int j = 0; j < 4; ++j) acc[i][j] = fmaf(ar[i], br[j], acc[i][j]);
        }
        __syncthreads();
    }
#pragma unroll
    for (int i = 0; i < 8; ++i) {
        int ri = (i < 4) ? (ty * 4 + i) : (64 + ty * 4 + (i - 4));
        float w = wsuminv[(bh << 11) + i0 + ri];
        *(float4*)(mid + (size_t)((bh << 11) + i0 + ri) * kDK + tx * 4) =
            make_float4(acc[i][0] * w, acc[i][1] * w, acc[i][2] * w, acc[i][3] * w);
    }
}

// ------------------- expmap0 + regather heads to (B,S,D) -------------------
__global__ __launch_bounds__(256) void expmap_gather(const float* __restrict__ mid,
                                                     float* __restrict__ outcat) {
    const int gid  = blockIdx.x * 4 + (threadIdx.x >> 6);
    const int lane = threadIdx.x & 63;
    const int bh = gid >> 11, s = gid & 2047;
    const int b = bh >> 3, h = bh & 7;
    float u = mid[(size_t)gid * kDK + lane];
    float sq = wave_sum64(u * u);
    float un = sqrtf(fmaxf(sq, 1e-15f));
    float coef = tanhf(un) / un;
    outcat[(size_t)(b * kS + s) * kD + h * kDK + lane] = u * coef;
}

} // namespace

extern "C" void kernel_launch(void* const* d_in, const int* in_sizes, int n_in,
                              void* d_out, int out_size, void* d_ws, size_t ws_size,
                              hipStream_t stream) {
    const float* q  = (const float*)d_in[0];
    const float* k  = (const float*)d_in[1];
    const float* v  = (const float*)d_in[2];
    const float* Wq = (const float*)d_in[3];
    const float* bq = (const float*)d_in[4];
    const float* Wk = (const float*)d_in[5];
    const float* bk = (const float*)d_in[6];
    const float* Wv = (const float*)d_in[7];
    const float* bv = (const float*)d_in[8];
    const float* Wo = (const float*)d_in[9];
    const float* bo = (const float*)d_in[10];

    float* out  = (float*)d_out;
    float* attn = out + (size_t)kM * kD;   // 2,097,152 floats of `out`, then attn

    constexpr size_t NBUF = (size_t)kM * kD; // 2,097,152 floats
    float* ws  = (float*)d_ws;
    float* A0  = ws;              // Qp  -> later mid
    float* A1  = ws + NBUF;       // Kp  -> later outcat
    float* A2  = ws + 2 * NBUF;   // Vp  -> later mx for final gemm
    float* A3  = ws + 3 * NBUF;   // mx scratch -> later LV
    float* qn2 = ws + 4 * NBUF;
    float* kn2 = qn2 + kBH * kS;
    float* wsi = kn2 + kBH * kS;

    dim3 gg(kM / 64, kD / 64);

    gemm_xwt<<<gg, 256, 0, stream>>>(q, Wq, A3);
    rowops<<<kM, 256, 0, stream>>>(q, A3, bq, A0);
    gemm_xwt<<<gg, 256, 0, stream>>>(k, Wk, A3);
    rowops<<<kM, 256, 0, stream>>>(k, A3, bk, A1);
    gemm_xwt<<<gg, 256, 0, stream>>>(v, Wv, A3);
    rowops<<<kM, 256, 0, stream>>>(v, A3, bv, A2);

    prep<<<(kBH * kS) / 4, 256, 0, stream>>>(A0, A1, A2, qn2, kn2, A3);

    dim3 sg(kS / 128, kS / 128, kBH);
    scores_k<<<sg, 256, 0, stream>>>(A0, A1, qn2, kn2, attn);

    softmax_k<<<kBH * kS, 256, 0, stream>>>(attn, wsi);

    dim3 pg(kS / 128, kBH);
    pv_k<<<pg, 256, 0, stream>>>(attn, A3, wsi, A0);

    expmap_gather<<<(kBH * kS) / 4, 256, 0, stream>>>(A0, A1);

    gemm_xwt<<<gg, 256, 0, stream>>>(A1, Wo, A2);
    rowops<<<kM, 256, 0, stream>>>(A1, A2, bo, out);
}

// Round 2
// 692.648 us; speedup vs baseline: 1.3052x; 1.3052x over previous
//
#include <hip/hip_runtime.h>
#include <math.h>

namespace {

constexpr int kB  = 2;
constexpr int kS  = 2048;
constexpr int kD  = 512;
constexpr int kH  = 8;
constexpr int kDK = 64;
constexpr int kM  = kB * kS;   // 4096 rows
constexpr int kBH = kB * kH;   // 16

__device__ __forceinline__ float wave_sum64(float v) {
#pragma unroll
    for (int o = 32; o > 0; o >>= 1) v += __shfl_xor(v, o, 64);
    return v;
}

#define MAXN_F  ((float)(1.0 - 1e-5))
#define ACLIP_F ((float)(1.0 - 1e-7))

// ------------------- GEMM: Y(M x 512) = X(M x 512) @ W(512 x 512)^T -------------------
__global__ __launch_bounds__(256) void gemm_xwt(const float* __restrict__ X,
                                                const float* __restrict__ W,
                                                float* __restrict__ Y) {
    __shared__ float As[16][68];
    __shared__ float Bs[16][68];
    const int bm = blockIdx.x * 64;
    const int bn = blockIdx.y * 64;
    const int tid = threadIdx.x;
    const int ty = tid >> 4, tx = tid & 15;
    const int lr = tid >> 2;
    const int lc = (tid & 3) * 4;
    float acc[4][4] = {};
    for (int k0 = 0; k0 < 512; k0 += 16) {
        float4 av = *(const float4*)(X + (size_t)(bm + lr) * 512 + k0 + lc);
        float4 bv = *(const float4*)(W + (size_t)(bn + lr) * 512 + k0 + lc);
        As[lc + 0][lr] = av.x; As[lc + 1][lr] = av.y; As[lc + 2][lr] = av.z; As[lc + 3][lr] = av.w;
        Bs[lc + 0][lr] = bv.x; Bs[lc + 1][lr] = bv.y; Bs[lc + 2][lr] = bv.z; Bs[lc + 3][lr] = bv.w;
        __syncthreads();
#pragma unroll
        for (int k = 0; k < 16; ++k) {
            float4 a = *(const float4*)&As[k][ty * 4];
            float4 b = *(const float4*)&Bs[k][tx * 4];
            float ar[4] = {a.x, a.y, a.z, a.w};
            float br[4] = {b.x, b.y, b.z, b.w};
#pragma unroll
            for (int i = 0; i < 4; ++i)
#pragma unroll
                for (int j = 0; j < 4; ++j) acc[i][j] = fmaf(ar[i], br[j], acc[i][j]);
        }
        __syncthreads();
    }
#pragma unroll
    for (int i = 0; i < 4; ++i) {
        *(float4*)(Y + (size_t)(bm + ty * 4 + i) * 512 + bn + tx * 4) =
            make_float4(acc[i][0], acc[i][1], acc[i][2], acc[i][3]);
    }
}

// --------- mobius_linear tail: res=matvec scale; mobius_add(res,b); project ---------
__global__ __launch_bounds__(256) void rowops(const float* __restrict__ X,
                                              const float* __restrict__ MX,
                                              const float* __restrict__ bvec,
                                              float* __restrict__ out) {
    __shared__ float4 red4[4];
    __shared__ float red1[4];
    const int row = blockIdx.x;
    const int tid = threadIdx.x;
    const float2 xv = ((const float2*)(X + (size_t)row * kD))[tid];
    const float2 mv = ((const float2*)(MX + (size_t)row * kD))[tid];
    const float2 bv = ((const float2*)bvec)[tid];
    float sx  = fmaf(xv.x, xv.x, xv.y * xv.y);
    float sm  = fmaf(mv.x, mv.x, mv.y * mv.y);
    float smb = fmaf(mv.x, bv.x, mv.y * bv.y);
    float sb  = fmaf(bv.x, bv.x, bv.y * bv.y);
#pragma unroll
    for (int o = 32; o > 0; o >>= 1) {
        sx  += __shfl_xor(sx, o, 64);
        sm  += __shfl_xor(sm, o, 64);
        smb += __shfl_xor(smb, o, 64);
        sb  += __shfl_xor(sb, o, 64);
    }
    if ((tid & 63) == 0) red4[tid >> 6] = make_float4(sx, sm, smb, sb);
    __syncthreads();
    {
        float4 r0 = red4[0], r1 = red4[1], r2 = red4[2], r3 = red4[3];
        sx  = r0.x + r1.x + r2.x + r3.x;
        sm  = r0.y + r1.y + r2.y + r3.y;
        smb = r0.z + r1.z + r2.z + r3.z;
        sb  = r0.w + r1.w + r2.w + r3.w;
    }
    float xn  = sqrtf(fmaxf(sx, 1e-15f));
    float mxn = sqrtf(fmaxf(sm, 1e-15f));
    float xc  = fminf(xn, ACLIP_F);
    float at  = 0.5f * logf((1.f + xc) / (1.f - xc));       // artanh(xn)
    float sc  = tanhf(mxn / xn * at) / mxn;                 // res = sc * mx
    if (sm == 0.f) sc = 0.f;                                // all(mx==0) branch
    float x2 = sc * sc * sm;
    float xy = sc * smb;
    float y2 = sb;
    float c1 = 1.f + 2.f * xy + y2;
    float c2 = 1.f - x2;
    float den = fmaxf(1.f + 2.f * xy + x2 * y2, 1e-15f);
    float idn = 1.f / den;
    float ux = (c1 * sc * mv.x + c2 * bv.x) * idn;
    float uy = (c1 * sc * mv.y + c2 * bv.y) * idn;
    float su = wave_sum64(fmaf(ux, ux, uy * uy));
    if ((tid & 63) == 0) red1[tid >> 6] = su;
    __syncthreads();
    su = (red1[0] + red1[1]) + (red1[2] + red1[3]);
    float n = sqrtf(fmaxf(su, 1e-15f));
    float f = (n > MAXN_F) ? (MAXN_F / n) : 1.f;
    ((float2*)(out + (size_t)row * kD))[tid] = make_float2(ux * f, uy * f);
}

// ---- prep: per-head-row |q|^2, |k|^2 and LV = logmap0(V_head), bh-major layout ----
__global__ __launch_bounds__(256) void prep(const float* __restrict__ Qp,
                                            const float* __restrict__ Kp,
                                            const float* __restrict__ Vp,
                                            float* __restrict__ qn2,
                                            float* __restrict__ kn2,
                                            float* __restrict__ LV) {
    const int gid  = blockIdx.x * 4 + (threadIdx.x >> 6); // 0..32767 = bh*2048+s
    const int lane = threadIdx.x & 63;
    const int bh = gid >> 11, s = gid & 2047;
    const int b = bh >> 3, h = bh & 7;
    const size_t src = (size_t)(b * kS + s) * kD + h * kDK + lane;
    float q = Qp[src], k = Kp[src], v = Vp[src];
    float sq = wave_sum64(q * q);
    float sk = wave_sum64(k * k);
    float sv = wave_sum64(v * v);
    if (lane == 0) { qn2[gid] = sq; kn2[gid] = sk; }
    float yn = sqrtf(fmaxf(sv, 1e-15f));
    float yc = fminf(yn, ACLIP_F);
    float coef = 0.5f * logf((1.f + yc) / (1.f - yc)) / yn;
    LV[(size_t)gid * kDK + lane] = v * coef;
}

// ----- scores+exp: per (b,h) 128x128 tile of exp(-dist/8), plus per-row partial sums -----
// LDS layout [d][m] with XOR swizzle m_phys = m ^ (d & 28): staging writes uniform
// 2-way (free), compute reads broadcast/2-way; f = d & 28 const-folds in unrolled loop.
__global__ __launch_bounds__(256) void scores_k(const float* __restrict__ Qp,
                                                const float* __restrict__ Kp,
                                                const float* __restrict__ qn2,
                                                const float* __restrict__ kn2,
                                                float* __restrict__ attn,
                                                float* __restrict__ part) {
    __shared__ float Qs[64][128];   // [d][m^swz]
    __shared__ float Ks[64][128];   // [d][n^swz]
    const int i0 = blockIdx.x * 128;
    const int j0 = blockIdx.y * 128;
    const int bh = blockIdx.z;
    const int b = bh >> 3, h = bh & 7;
    const int tid = threadIdx.x;
    for (int t = tid; t < 2048; t += 256) {
        const int r = t >> 4;
        const int c = (t & 15) * 4;
        const int mp = r ^ (c & 28);
        float4 qv = *(const float4*)(Qp + (size_t)(b * kS + i0 + r) * kD + h * kDK + c);
        float4 kv = *(const float4*)(Kp + (size_t)(b * kS + j0 + r) * kD + h * kDK + c);
        Qs[c + 0][mp] = qv.x; Qs[c + 1][mp] = qv.y; Qs[c + 2][mp] = qv.z; Qs[c + 3][mp] = qv.w;
        Ks[c + 0][mp] = kv.x; Ks[c + 1][mp] = kv.y; Ks[c + 2][mp] = kv.z; Ks[c + 3][mp] = kv.w;
    }
    __syncthreads();
    const int ty = tid >> 4, tx = tid & 15;
    float acc[8][8] = {};
#pragma unroll 8
    for (int d = 0; d < 64; ++d) {
        const int f = d & 28;
        float4 a0 = *(const float4*)&Qs[d][(ty * 4) ^ f];
        float4 a1 = *(const float4*)&Qs[d][64 + ((ty * 4) ^ f)];
        float4 b0 = *(const float4*)&Ks[d][(tx * 4) ^ f];
        float4 b1 = *(const float4*)&Ks[d][64 + ((tx * 4) ^ f)];
        float ar[8] = {a0.x, a0.y, a0.z, a0.w, a1.x, a1.y, a1.z, a1.w};
        float br[8] = {b0.x, b0.y, b0.z, b0.w, b1.x, b1.y, b1.z, b1.w};
#pragma unroll
        for (int i = 0; i < 8; ++i)
#pragma unroll
            for (int j = 0; j < 8; ++j) acc[i][j] = fmaf(ar[i], br[j], acc[i][j]);
    }
    float x2r[8], y2c[8];
#pragma unroll
    for (int i = 0; i < 8; ++i) {
        int ri = (i < 4) ? (ty * 4 + i) : (64 + ty * 4 + (i - 4));
        x2r[i] = qn2[(bh << 11) + i0 + ri];
    }
#pragma unroll
    for (int j = 0; j < 8; ++j) {
        int cj = (j < 4) ? (tx * 4 + j) : (64 + tx * 4 + (j - 4));
        y2c[j] = kn2[(bh << 11) + j0 + cj];
    }
#pragma unroll
    for (int i = 0; i < 8; ++i) {
        int ri = (i < 4) ? (ty * 4 + i) : (64 + ty * 4 + (i - 4));
        float* orow = attn + (size_t)((bh << 11) + i0 + ri) * kS + j0;
        float o[8];
        float rs = 0.f;
#pragma unroll
        for (int j = 0; j < 8; ++j) {
            float xy = acc[i][j];
            float x2 = x2r[i], y2 = y2c[j];
            float A  = 1.f - 2.f * xy + y2;
            float Bc = 1.f - x2;
            float num2 = A * A * x2 + Bc * Bc * y2 - 2.f * A * Bc * xy;
            float den  = fmaxf(1.f - 2.f * xy + x2 * y2, 1e-15f);
            float sn   = __builtin_amdgcn_sqrtf(fmaxf(num2, 0.f));
            float dm   = den - sn;
            dm = fmaxf(dm, (den + sn) * 5e-8f);               // == artanh clip at 1-1e-7
            float rr = (den + sn) * __builtin_amdgcn_rcpf(dm); // (1+t)/(1-t)
            // exp(-dist/8) = rr^(-1/8) = exp2(-log2(rr)/8)
            float e = __builtin_amdgcn_exp2f(-0.125f * __builtin_amdgcn_logf(rr));
            o[j] = e;
            rs += e;
        }
        *(float4*)(orow + tx * 4)      = make_float4(o[0], o[1], o[2], o[3]);
        *(float4*)(orow + 64 + tx * 4) = make_float4(o[4], o[5], o[6], o[7]);
        // reduce rs over the 16 tx-lanes sharing this row (lanes are 16-aligned groups)
#pragma unroll
        for (int off = 8; off > 0; off >>= 1) rs += __shfl_xor(rs, off, 64);
        if (tx == 0) part[(size_t)((bh << 11) + i0 + ri) * 16 + blockIdx.y] = rs;
    }
}

// ------------------- invS1[row] = 1 / sum_j exp-partials -------------------
__global__ __launch_bounds__(256) void finalize_inv(const float* __restrict__ part,
                                                    float* __restrict__ invS1) {
    const int row = blockIdx.x * 256 + threadIdx.x;
    const float4* p = (const float4*)(part + (size_t)row * 16);
    float4 a = p[0], b = p[1], c = p[2], d = p[3];
    float s = ((a.x + a.y) + (a.z + a.w)) + ((b.x + b.y) + (b.z + b.w)) +
              ((c.x + c.y) + (c.z + c.w)) + ((d.x + d.y) + (d.z + d.w));
    invS1[row] = 1.f / s;
}

// ---- pv: normalize attn tile (write back final attn) + mid = attn @ LV, per (b,h) ----
__global__ __launch_bounds__(256) void pv_k(float* __restrict__ attn,
                                            const float* __restrict__ LV,
                                            const float* __restrict__ invS1,
                                            float* __restrict__ mid) {
    __shared__ float As[64][128];  // [k][m^swz]
    __shared__ float Ls[64][68];   // [k][n]
    const int i0 = blockIdx.x * 128;
    const int bh = blockIdx.y;
    const int tid = threadIdx.x;
    const int ty = tid >> 4, tx = tid & 15;
    float acc[8][4] = {};
    for (int k0 = 0; k0 < kS; k0 += 64) {
        for (int t = tid; t < 2048; t += 256) {
            const int r = t >> 4;
            const int c = (t & 15) * 4;
            const int mp = r ^ (c & 28);
            float* ap = attn + (size_t)((bh << 11) + i0 + r) * kS + k0 + c;
            float4 av = *(const float4*)ap;
            float is = invS1[(bh << 11) + i0 + r];
            av.x *= is; av.y *= is; av.z *= is; av.w *= is;
            As[c + 0][mp] = av.x; As[c + 1][mp] = av.y; As[c + 2][mp] = av.z; As[c + 3][mp] = av.w;
            *(float4*)ap = av;                    // final normalized attn output
        }
        for (int t = tid; t < 1024; t += 256) {
            const int r = t >> 4;
            const int c = (t & 15) * 4;
            *(float4*)&Ls[r][c] = *(const float4*)(LV + (size_t)((bh << 11) + k0 + r) * kDK + c);
        }
        __syncthreads();
#pragma unroll 8
        for (int k = 0; k < 64; ++k) {
            const int f = k & 28;
            float4 a0 = *(const float4*)&As[k][(ty * 4) ^ f];
            float4 a1 = *(const float4*)&As[k][64 + ((ty * 4) ^ f)];
            float4 bb = *(const float4*)&Ls[k][tx * 4];
            float ar[8] = {a0.x, a0.y, a0.z, a0.w, a1.x, a1.y, a1.z, a1.w};
            float br[4] = {bb.x, bb.y, bb.z, bb.w};
#pragma unroll
            for (int i = 0; i < 8; ++i)
#pragma unroll
                for (int j = 0; j < 4; ++j) acc[i][j] = fmaf(ar[i], br[j], acc[i][j]);
        }
        __syncthreads();
    }
#pragma unroll
    for (int i = 0; i < 8; ++i) {
        int ri = (i < 4) ? (ty * 4 + i) : (64 + ty * 4 + (i - 4));
        *(float4*)(mid + (size_t)((bh << 11) + i0 + ri) * kDK + tx * 4) =
            make_float4(acc[i][0], acc[i][1], acc[i][2], acc[i][3]);
    }
}

// ------------------- expmap0 + regather heads to (B,S,D) -------------------
__global__ __launch_bounds__(256) void expmap_gather(const float* __restrict__ mid,
                                                     float* __restrict__ outcat) {
    const int gid  = blockIdx.x * 4 + (threadIdx.x >> 6);
    const int lane = threadIdx.x & 63;
    const int bh = gid >> 11, s = gid & 2047;
    const int b = bh >> 3, h = bh & 7;
    float u = mid[(size_t)gid * kDK + lane];
    float sq = wave_sum64(u * u);
    float un = sqrtf(fmaxf(sq, 1e-15f));
    float coef = tanhf(un) / un;
    outcat[(size_t)(b * kS + s) * kD + h * kDK + lane] = u * coef;
}

} // namespace

extern "C" void kernel_launch(void* const* d_in, const int* in_sizes, int n_in,
                              void* d_out, int out_size, void* d_ws, size_t ws_size,
                              hipStream_t stream) {
    const float* q  = (const float*)d_in[0];
    const float* k  = (const float*)d_in[1];
    const float* v  = (const float*)d_in[2];
    const float* Wq = (const float*)d_in[3];
    const float* bq = (const float*)d_in[4];
    const float* Wk = (const float*)d_in[5];
    const float* bk = (const float*)d_in[6];
    const float* Wv = (const float*)d_in[7];
    const float* bv = (const float*)d_in[8];
    const float* Wo = (const float*)d_in[9];
    const float* bo = (const float*)d_in[10];

    float* out  = (float*)d_out;
    float* attn = out + (size_t)kM * kD;   // out (2M floats), then attn (64M floats)

    constexpr size_t NBUF = (size_t)kM * kD; // 2,097,152 floats
    float* ws  = (float*)d_ws;
    float* A0  = ws;              // Qp  -> later mid
    float* A1  = ws + NBUF;       // Kp  -> later outcat
    float* A2  = ws + 2 * NBUF;   // Vp  -> later part/invS1 -> later mx for final gemm
    float* A3  = ws + 3 * NBUF;   // mx scratch -> later LV
    float* qn2 = ws + 4 * NBUF;
    float* kn2 = qn2 + (size_t)kBH * kS;
    float* part  = A2;                              // 32768*16 floats (Vp is dead by then)
    float* invS1 = A2 + (size_t)kBH * kS * 16;      // 32768 floats

    dim3 gg(kM / 64, kD / 64);

    gemm_xwt<<<gg, 256, 0, stream>>>(q, Wq, A3);
    rowops<<<kM, 256, 0, stream>>>(q, A3, bq, A0);
    gemm_xwt<<<gg, 256, 0, stream>>>(k, Wk, A3);
    rowops<<<kM, 256, 0, stream>>>(k, A3, bk, A1);
    gemm_xwt<<<gg, 256, 0, stream>>>(v, Wv, A3);
    rowops<<<kM, 256, 0, stream>>>(v, A3, bv, A2);

    prep<<<(kBH * kS) / 4, 256, 0, stream>>>(A0, A1, A2, qn2, kn2, A3);

    dim3 sg(kS / 128, kS / 128, kBH);
    scores_k<<<sg, 256, 0, stream>>>(A0, A1, qn2, kn2, attn, part);

    finalize_inv<<<(kBH * kS) / 256, 256, 0, stream>>>(part, invS1);

    dim3 pg(kS / 128, kBH);
    pv_k<<<pg, 256, 0, stream>>>(attn, A3, invS1, A0);

    expmap_gather<<<(kBH * kS) / 4, 256, 0, stream>>>(A0, A1);

    gemm_xwt<<<gg, 256, 0, stream>>>(A1, Wo, A2);
    rowops<<<kM, 256, 0, stream>>>(A1, A2, bo, out);
}